// Round 9
// baseline (363.072 us; speedup 1.0000x reference)
//
#include <hip/hip_runtime.h>

#define NSEG 511
#define NROWS 8            // rows 8..15 only
#define ROW0 8
#define K0 21              // first needed freq bin
#define KEND 500           // bins k with 20 < k < 500
#define NFREQ 479
#define ACC_STRIDE 512     // padded per-row accumulator stride
#define ACC_ELEMS (2 * NROWS * ACC_STRIDE)   // one replica
#define NREP 8             // accumulator replicas
#define SPB 2              // segments per block
#define NGROUPS 256        // ceil(511/2)
#define NBLOCKS (2 * NROWS * NGROUPS)

// XOR swizzle for the FFT buffer (keeps quads contiguous).
__device__ __forceinline__ int sw(int i) { return i ^ (((i >> 5) & 7) << 2); }
// XOR swizzle for the natural-order region: de-conflicts stage-D scatter
// writes while keeping linear reads conflict-free.
__device__ __forceinline__ int ms(int m) { return m ^ ((m >> 6) & 7); }

__device__ __forceinline__ float2 cmul(float2 a, float2 b) {
    return make_float2(fmaf(a.x, b.x, -a.y * b.y), fmaf(a.x, b.y, a.y * b.x));
}
__device__ __forceinline__ float2 cadd(float2 a, float2 b) { return make_float2(a.x + b.x, a.y + b.y); }
__device__ __forceinline__ float2 csub(float2 a, float2 b) { return make_float2(a.x - b.x, a.y - b.y); }

// In-register 8-point DFT (DIF).
__device__ __forceinline__ void dft8(float2& x0, float2& x1, float2& x2, float2& x3,
                                     float2& x4, float2& x5, float2& x6, float2& x7) {
    const float C45 = 0.70710678118654752440f;
    float2 t0 = cadd(x0, x4), u0 = csub(x0, x4);
    float2 t1 = cadd(x1, x5), u1 = csub(x1, x5);
    float2 t2 = cadd(x2, x6), u2 = csub(x2, x6);
    float2 t3 = cadd(x3, x7), u3 = csub(x3, x7);
    float2 s0 = cadd(t0, t2), d0 = csub(t0, t2);
    float2 s1 = cadd(t1, t3), d1 = csub(t1, t3);
    float2 v1 = make_float2(C45 * (u1.x + u1.y), C45 * (u1.y - u1.x));
    float2 v2 = make_float2(u2.y, -u2.x);
    float2 v3 = make_float2(C45 * (u3.y - u3.x), -C45 * (u3.x + u3.y));
    float2 s2 = cadd(u0, v2), d2 = csub(u0, v2);
    float2 s3 = cadd(v1, v3), d3 = csub(v1, v3);
    float2 mid1 = make_float2(d1.y, -d1.x);   // -i * d1
    float2 mid3 = make_float2(d3.y, -d3.x);   // -i * d3
    x0 = cadd(s0, s1); x4 = csub(s0, s1);
    x2 = cadd(d0, mid1); x6 = csub(d0, mid1);
    x1 = cadd(s2, s3); x5 = csub(s2, s3);
    x3 = cadd(d2, mid3); x7 = csub(d2, mid3);
}

// x[p] *= W^p with W = (c, s) given.
__device__ __forceinline__ void twiddle8cs(float2& x1, float2& x2, float2& x3, float2& x4,
                                           float2& x5, float2& x6, float2& x7,
                                           float c, float s) {
    float2 w1 = make_float2(c, s);
    float2 w2 = cmul(w1, w1);
    float2 w3 = cmul(w2, w1);
    float2 w4 = cmul(w2, w2);
    float2 w5 = cmul(w4, w1);
    float2 w6 = cmul(w3, w3);
    float2 w7 = cmul(w4, w3);
    x1 = cmul(x1, w1); x2 = cmul(x2, w2); x3 = cmul(x3, w3);
    x4 = cmul(x4, w4); x5 = cmul(x5, w5); x6 = cmul(x6, w6);
    x7 = cmul(x7, w7);
}

// One block = one (signal, row, 2 consecutive segments). Register 2048-pt
// complex FFT (radices [8,8,8,4-fused]), 16 KiB LDS (stage-D natural-order
// region merged into the FFT buffer via register staging), VGPRs capped for
// 8 waves/SIMD residency. Power accumulated in registers; one atomic flush.
__global__ __launch_bounds__(256, 8)
void psd_kernel(const float* __restrict__ pred,
                const float* __restrict__ target,
                float* __restrict__ acc) {
    __shared__ float2 buf[2048];   // 16 KiB total

    const int bid = blockIdx.x;
    const int grp = bid % NGROUPS;
    const int row = (bid / NGROUPS) % NROWS + ROW0;
    const int sig = bid / (NGROUPS * NROWS);   // 0 = res (target-pred), 1 = target
    const int tid = threadIdx.x;
    const int seg0 = grp * SPB;
    const int ns = (seg0 + SPB <= NSEG) ? SPB : (NSEG - seg0);   // 2 (last group: 1)
    float* accR = acc + (bid & (NREP - 1)) * ACC_ELEMS;

    const float2* t2p = (const float2*)target;
    const float2* p2p = (const float2*)pred;

    // Complex point m of segment s: real samples at batch row 2(seg0+s)+(m>>9),
    // float2 offset row*512 + (m&511). m = tid + 256*R.
    const int base = 2 * seg0 * 8192 + row * 512 + tid;
#define LOADRAW(X, IDX)                                                      \
    {                                                                        \
        int _i = (IDX);                                                      \
        float2 v = t2p[_i];                                                  \
        if (sig == 0) { float2 p = p2p[_i]; v.x -= p.x; v.y -= p.y; }        \
        X = v;                                                               \
    }
    float2 r0, r1, r2, r3, r4, r5, r6, r7;
    LOADRAW(r0, base)
    LOADRAW(r1, base + 256)
    LOADRAW(r2, base + 8192)
    LOADRAW(r3, base + 8448)
    LOADRAW(r4, base + 16384)
    LOADRAW(r5, base + 16640)
    LOADRAW(r6, base + 24576)
    LOADRAW(r7, base + 24832)

    // ---- minimal hoisted trig (8 scalars live across the loop) ----
    const float WA = 3.06796157577128245e-3f;      // 2*pi/2048
    float sa, ca;
    __sincosf((float)tid * WA, &sa, &ca);          // window base; stage-A tw = (ca,-sa)
    float sb, cb;
    __sincosf((float)(tid & 31) * -2.45436926061702596e-2f, &sb, &cb);  // -2*pi/256
    float sn0, cs0;
    __sincosf(-1.53398078788564123e-3f * (float)(K0 + tid), &sn0, &cs0);  // -2*pi*k/4096

    float pw1 = 0.0f, pw2 = 0.0f;   // register power accumulators (2 bins/thread)
    float4* b4 = (float4*)buf;

    #pragma unroll 1
    for (int s = 0; s < ns; ++s) {
        // ---- window (weights recomputed from (ca,sa): keeps them out of the
        // live-across-loop register set; VALU cost hidden under stalls — R7)
        const float CD = 0.99999882344642529f;     // cos(pi/2048)
        const float SD = 1.53398018628476550e-3f;  // sin(pi/2048)
        const float H  = 0.70710678118654752440f;  // sqrt(2)/2
        float2 x0, x1, x2, x3, x4, x5, x6, x7;
#define WINR(X, RV, CE, SE)                                                  \
        { float cr = (CE), sr = (SE);                                        \
          X = make_float2(RV.x * (1.0f - cr),                                \
                          RV.y * (1.0f - (cr * CD - sr * SD))); }
        WINR(x0, r0, ca, sa)
        WINR(x1, r1, H * (ca - sa), H * (sa + ca))
        WINR(x2, r2, -sa, ca)
        WINR(x3, r3, -H * (ca + sa), H * (ca - sa))
        WINR(x4, r4, -ca, -sa)
        WINR(x5, r5, H * (sa - ca), -H * (sa + ca))
        WINR(x6, r6, sa, -ca)
        WINR(x7, r7, H * (ca + sa), H * (sa - ca))
#undef WINR

        // ---- shift overlap half + prefetch next segment's new half
        if (s + 1 < ns) {
            r0 = r4; r1 = r5; r2 = r6; r3 = r7;
            int nb = base + (s + 1) * 16384;
            LOADRAW(r4, nb + 16384)
            LOADRAW(r5, nb + 16640)
            LOADRAW(r6, nb + 24576)
            LOADRAW(r7, nb + 24832)
        }

        // ---- stage A: radix-8 stride 256, twiddle W2048^{tid*p} = (ca,-sa)^p
        dft8(x0, x1, x2, x3, x4, x5, x6, x7);
        twiddle8cs(x1, x2, x3, x4, x5, x6, x7, ca, -sa);
        buf[sw(tid)]        = x0;
        buf[sw(tid + 256)]  = x1;
        buf[sw(tid + 512)]  = x2;
        buf[sw(tid + 768)]  = x3;
        buf[sw(tid + 1024)] = x4;
        buf[sw(tid + 1280)] = x5;
        buf[sw(tid + 1536)] = x6;
        buf[sw(tid + 1792)] = x7;
        __syncthreads();

        // ---- stage B: radix-8 stride 32 within each 256-subFFT
        {
            const int baseB = (tid & 31) + 256 * (tid >> 5);
            x0 = buf[sw(baseB)];
            x1 = buf[sw(baseB + 32)];
            x2 = buf[sw(baseB + 64)];
            x3 = buf[sw(baseB + 96)];
            x4 = buf[sw(baseB + 128)];
            x5 = buf[sw(baseB + 160)];
            x6 = buf[sw(baseB + 192)];
            x7 = buf[sw(baseB + 224)];
            dft8(x0, x1, x2, x3, x4, x5, x6, x7);
            twiddle8cs(x1, x2, x3, x4, x5, x6, x7, cb, sb);
            buf[sw(baseB)]       = x0;
            buf[sw(baseB + 32)]  = x1;
            buf[sw(baseB + 64)]  = x2;
            buf[sw(baseB + 96)]  = x3;
            buf[sw(baseB + 128)] = x4;
            buf[sw(baseB + 160)] = x5;
            buf[sw(baseB + 192)] = x6;
            buf[sw(baseB + 224)] = x7;
        }
        __syncthreads();

        // ---- stage C: radix-8 stride 4 within each 32-subFFT
        {
            const int baseC = (tid & 3) + 32 * ((tid >> 2) & 7) + 256 * (tid >> 5);
            x0 = buf[sw(baseC)];
            x1 = buf[sw(baseC + 4)];
            x2 = buf[sw(baseC + 8)];
            x3 = buf[sw(baseC + 12)];
            x4 = buf[sw(baseC + 16)];
            x5 = buf[sw(baseC + 20)];
            x6 = buf[sw(baseC + 24)];
            x7 = buf[sw(baseC + 28)];
            dft8(x0, x1, x2, x3, x4, x5, x6, x7);
            // twiddle W32^{mq*i}, mq = tid&3: constants
            const float TC1 = 0.98078528040323044913f, TS1 = -0.19509032201612826785f;
            const float TC2 = 0.92387953251128675613f, TS2 = -0.38268343236508977173f;
            const float TC3 = 0.83146961230254523708f, TS3 = -0.55557023301960222474f;
            int mq = tid & 3;
            float cc = (mq & 2) ? ((mq & 1) ? TC3 : TC2) : ((mq & 1) ? TC1 : 1.0f);
            float ssv = (mq & 2) ? ((mq & 1) ? TS3 : TS2) : ((mq & 1) ? TS1 : 0.0f);
            twiddle8cs(x1, x2, x3, x4, x5, x6, x7, cc, ssv);
            buf[sw(baseC)]      = x0;
            buf[sw(baseC + 4)]  = x1;
            buf[sw(baseC + 8)]  = x2;
            buf[sw(baseC + 12)] = x3;
            buf[sw(baseC + 16)] = x4;
            buf[sw(baseC + 20)] = x5;
            buf[sw(baseC + 24)] = x6;
            buf[sw(baseC + 28)] = x7;
        }
        __syncthreads();

        // ---- stage D fused with digit-reversal, nat region merged into buf:
        // read both quads into registers, barrier, then write X0 -> buf[ms(m)],
        // X3 -> buf[512+ms(m)] (m = natural bin index, quad n: m = 64(n&7)+8((n>>3)&7)+(n>>6)).
        {
            int q1 = sw(4 * tid) >> 1;
            int q2 = sw(4 * (tid + 256)) >> 1;
            float4 lo1 = b4[q1], hi1 = b4[q1 + 1];
            float4 lo2 = b4[q2], hi2 = b4[q2 + 1];
            __syncthreads();   // all quads read before overwriting buf[0..1023]
            int m1 = 64 * (tid & 7) + 8 * ((tid >> 3) & 7) + (tid >> 6);
            int m2 = m1 + (((tid + 256) >> 6) - (tid >> 6));  // n2=tid+256: same low digits, p+... 
            // recompute m2 exactly (n2 = tid + 256 only changes bits >=6 pattern):
            m2 = 64 * ((tid + 256) & 7) + 8 * (((tid + 256) >> 3) & 7) + ((tid + 256) >> 6);
            float2 X0a = make_float2((lo1.x + hi1.x) + (lo1.z + hi1.z),
                                     (lo1.y + hi1.y) + (lo1.w + hi1.w));
            float2 X3a = make_float2((lo1.x - hi1.x) - (lo1.w - hi1.w),
                                     (lo1.y - hi1.y) + (lo1.z - hi1.z));
            float2 X0b = make_float2((lo2.x + hi2.x) + (lo2.z + hi2.z),
                                     (lo2.y + hi2.y) + (lo2.w + hi2.w));
            float2 X3b = make_float2((lo2.x - hi2.x) - (lo2.w - hi2.w),
                                     (lo2.y - hi2.y) + (lo2.z - hi2.z));
            int a1 = ms(m1), a2 = ms(m2);
            buf[a1] = X0a;  buf[512 + a1] = X3a;
            buf[a2] = X0b;  buf[512 + a2] = X3b;
        }
        __syncthreads();

        // ---- untangle + power, accumulate in registers (linear reads)
        {
            int k = K0 + tid;                       // 21..276, always < 500
            float2 zk = buf[ms(k)];
            float2 zn = buf[512 + ms(512 - k)];     // Z[2048-k]
            float Ex = 0.5f * (zk.x + zn.x);
            float Ey = 0.5f * (zk.y - zn.y);
            float Ox = 0.5f * (zk.y + zn.y);
            float Oy = -0.5f * (zk.x - zn.x);
            float xr = Ex + Ox * cs0 - Oy * sn0;
            float xi = Ey + Ox * sn0 + Oy * cs0;
            pw1 += xr * xr + xi * xi;
        }
        if (tid < KEND - K0 - 256) {                // k2 = K0+256+tid < 500
            // untangle twiddle for k+256 = -pi/8 rotation of (cs0,sn0)
            const float CU = 0.98078528040323044913f;   // cos(pi/8)
            const float SU = 0.19509032201612826785f;   // sin(pi/8)
            float cs1 = cs0 * CU + sn0 * SU;
            float sn1 = sn0 * CU - cs0 * SU;
            int k = K0 + 256 + tid;
            float2 zk = buf[ms(k)];
            float2 zn = buf[512 + ms(512 - k)];
            float Ex = 0.5f * (zk.x + zn.x);
            float Ey = 0.5f * (zk.y - zn.y);
            float Ox = 0.5f * (zk.y + zn.y);
            float Oy = -0.5f * (zk.x - zn.x);
            float xr = Ex + Ox * cs1 - Oy * sn1;
            float xi = Ey + Ox * sn1 + Oy * cs1;
            pw2 += xr * xr + xi * xi;
        }
        __syncthreads();   // untangle reads done before next segment's stage A
    }

    // ---- single atomic flush per thread
    {
        int i0 = (sig * NROWS + (row - ROW0)) * ACC_STRIDE;
        atomicAdd(&accR[i0 + tid], pw1);
        if (tid < KEND - K0 - 256) atomicAdd(&accR[i0 + 256 + tid], pw2);
    }
#undef LOADRAW
}

// Single block: out = sum over (row,k) of P_res/P_tgt, / 240.
// (dfreq=1, scale=480, mean(last 8)*16 => 2/480 = 1/240; /T cancels in ratio)
__global__ __launch_bounds__(256)
void reduce_kernel(const float* __restrict__ acc, float* __restrict__ out) {
    __shared__ float sh[256];
    int tid = threadIdx.x;
    float sum = 0.0f;
    for (int n = tid; n < NROWS * NFREQ; n += 256) {
        int r = n / NFREQ, k = n % NFREQ;
        float num = 0.0f, den = 0.0f;
        #pragma unroll
        for (int rep = 0; rep < NREP; ++rep) {
            num += acc[rep * ACC_ELEMS + r * ACC_STRIDE + k];
            den += acc[rep * ACC_ELEMS + (NROWS + r) * ACC_STRIDE + k];
        }
        sum += num / den;
    }
    sh[tid] = sum;
    __syncthreads();
    for (int s = 128; s > 0; s >>= 1) {
        if (tid < s) sh[tid] += sh[tid + s];
        __syncthreads();
    }
    if (tid == 0) out[0] = sh[0] * (1.0f / 240.0f);
}

extern "C" void kernel_launch(void* const* d_in, const int* in_sizes, int n_in,
                              void* d_out, int out_size, void* d_ws, size_t ws_size,
                              hipStream_t stream) {
    const float* pred = (const float*)d_in[0];
    const float* target = (const float*)d_in[1];
    float* acc = (float*)d_ws;   // NREP replicas of [2][NROWS][ACC_STRIDE] = 256 KiB

    hipMemsetAsync(acc, 0, NREP * ACC_ELEMS * sizeof(float), stream);
    psd_kernel<<<NBLOCKS, 256, 0, stream>>>(pred, target, acc);
    reduce_kernel<<<1, 256, 0, stream>>>(acc, (float*)d_out);
}